// Round 1
// 345.291 us; speedup vs baseline: 1.0392x; 1.0392x over previous
//
#include <hip/hip_runtime.h>
#include <hip/hip_bf16.h>
#include <cstdint>

// Problem shape (Transducer joint network):
//   enc (4,160,640) fp32, dec (4,80,640) fp32, W1 (1280,640), b1 (640),
//   W2 (640,1024), b2 (1024).  out = (4,160,80,1024) fp32 = 52.4M floats.
#define B_    4
#define T_    160
#define U_    80
#define D_    640      // De = Dd = inner
#define V_    1024
#define BT_   640      // B*T
#define BU_   320      // B*U
#define M_    51200    // B*T*U

typedef __bf16 bf16x8 __attribute__((ext_vector_type(8)));
typedef float floatx4 __attribute__((ext_vector_type(4)));

__device__ __forceinline__ void g2l16(const void* g, void* l) {
    __builtin_amdgcn_global_load_lds((const __attribute__((address_space(1))) void*)g,
                                     (__attribute__((address_space(3))) void*)l,
                                     16, 0, 0);
}

__device__ __forceinline__ float fast_tanh(float x) {
    float e = __builtin_amdgcn_exp2f(x * 2.8853900817779268f); // 2*log2(e)
    return 1.0f - 2.0f * __builtin_amdgcn_rcpf(e + 1.0f);
}

// ---------------------------------------------------------------------------
// Kernel 1: fp32 projections (unchanged this round).
// ---------------------------------------------------------------------------
__global__ __launch_bounds__(256) void proj_kernel(
    const float* __restrict__ enc, const float* __restrict__ dec,
    const float* __restrict__ W1,
    float* __restrict__ encp, float* __restrict__ decp) {
    __shared__ float As[32][36];
    __shared__ float Ws[32][36];

    const int rt = blockIdx.y;
    const int ct = blockIdx.x;
    const float* Asrc;
    const float* Wsrc;
    float* Cdst;
    if (rt < 20) { Asrc = enc + (size_t)rt * 32 * D_;        Wsrc = W1;             Cdst = encp + (size_t)rt * 32 * D_; }
    else         { Asrc = dec + (size_t)(rt - 20) * 32 * D_; Wsrc = W1 + D_ * D_;   Cdst = decp + (size_t)(rt - 20) * 32 * D_; }

    const int tid = threadIdx.x;
    const int ar = tid >> 3, ac = (tid & 7) * 4;
    const int tr = tid >> 4, tc = tid & 15;

    float a00 = 0.f, a01 = 0.f, a10 = 0.f, a11 = 0.f;
    for (int k0 = 0; k0 < D_; k0 += 32) {
        __syncthreads();
        *(floatx4*)&As[ar][ac] = *(const floatx4*)&Asrc[(size_t)ar * D_ + k0 + ac];
        *(floatx4*)&Ws[ar][ac] = *(const floatx4*)&Wsrc[(size_t)(k0 + ar) * D_ + ct * 32 + ac];
        __syncthreads();
#pragma unroll
        for (int kk = 0; kk < 32; kk++) {
            float x0 = As[tr * 2][kk], x1 = As[tr * 2 + 1][kk];
            float w0 = Ws[kk][tc * 2], w1 = Ws[kk][tc * 2 + 1];
            a00 += x0 * w0; a01 += x0 * w1;
            a10 += x1 * w0; a11 += x1 * w1;
        }
    }
    const int cc = ct * 32 + tc * 2;
    Cdst[(size_t)(tr * 2) * D_ + cc]     = a00;
    Cdst[(size_t)(tr * 2) * D_ + cc + 1] = a01;
    Cdst[(size_t)(tr * 2 + 1) * D_ + cc]     = a10;
    Cdst[(size_t)(tr * 2 + 1) * D_ + cc + 1] = a11;
}

// ---------------------------------------------------------------------------
// Kernel 2: W2 (640x1024 fp32, KxN) -> W2t (1024x640 bf16, NxK). Unchanged.
// ---------------------------------------------------------------------------
__global__ __launch_bounds__(256) void w2t_kernel(
    const float* __restrict__ W2, __bf16* __restrict__ W2t) {
    __shared__ __bf16 tile[32][33];
    const int vt = blockIdx.x;
    const int kt = blockIdx.y;
    const int tx = threadIdx.x & 31, ty = threadIdx.x >> 5;
#pragma unroll
    for (int i = 0; i < 4; i++)
        tile[ty + i * 8][tx] = (__bf16)W2[(size_t)(kt * 32 + ty + i * 8) * V_ + vt * 32 + tx];
    __syncthreads();
#pragma unroll
    for (int i = 0; i < 4; i++)
        W2t[(size_t)(vt * 32 + ty + i * 8) * D_ + kt * 32 + tx] = tile[tx][ty + i * 8];
}

// ---------------------------------------------------------------------------
// Kernel 3: hidden = tanh(encp + decp + b1) -> bf16. Unchanged.
// ---------------------------------------------------------------------------
__global__ __launch_bounds__(256) void hidden_kernel(
    const float* __restrict__ encp, const float* __restrict__ decp,
    const float* __restrict__ b1, __bf16* __restrict__ H) {
    const unsigned g = blockIdx.x * 256u + threadIdx.x;
    const unsigned row = g / 80u;
    const unsigned hg  = g % 80u;
    const unsigned u   = row % 80u;
    const unsigned bt  = row / 80u;
    const unsigned b   = bt / 160u;

    const float* ep = encp + (size_t)bt * D_ + hg * 8;
    const float* dp = decp + (size_t)(b * 80u + u) * D_ + hg * 8;
    const float* bp = b1 + hg * 8;

    floatx4 e0 = *(const floatx4*)ep,       e1 = *(const floatx4*)(ep + 4);
    floatx4 d0 = *(const floatx4*)dp,       d1 = *(const floatx4*)(dp + 4);
    floatx4 c0 = *(const floatx4*)bp,       c1 = *(const floatx4*)(bp + 4);

    bf16x8 hv;
#pragma unroll
    for (int i = 0; i < 4; i++) hv[i]     = (__bf16)fast_tanh(e0[i] + d0[i] + c0[i]);
#pragma unroll
    for (int i = 0; i < 4; i++) hv[i + 4] = (__bf16)fast_tanh(e1[i] + d1[i] + c1[i]);

    *(bf16x8*)(H + (size_t)g * 8) = hv;
}

// ---------------------------------------------------------------------------
// Kernel 4: C[51200x1024] = H[51200x640] @ W2t[1024x640]^T + b2.
// 256x256 8-phase schedule (T1+T2+T3+T4+T5, m201 template ported):
//   BM=BN=256, BK=64, 512 threads = 8 waves (2M x 4N), per-wave 128x64 out.
//   LDS 128KB: A/B each 2 K-tile buffers of 256x64 bf16, XOR-swizzled
//   (16B slot ^= row&7) via pre-swizzled global source + linear g2l dest.
//   Per phase: 12 ds_read_b128 || 0-2 half-slice prefetch (g2l16 x2 each)
//   -> barrier -> setprio(1) 16 MFMA setprio(0) -> barrier.
//   vmcnt(4) only at phases 4 & 8 (counted, never 0 in steady state).
//
// Quadrant remap (so each phase consumes CONTIGUOUS 128-row half-slices):
//   wave wr owns A rows {wr*64+[0,64)} u {128+wr*64+[0,64)}   (qm = slice)
//   wave wc owns B rows {wc*32+[0,32)} u {128+wc*32+[0,32)}   (qn = slice)
// Slice schedule per iter (tiles 2i->buf0, 2i+1->buf1), verified RAW/WAR:
//   stage: P0: t1.A1,B1 | P2: t2.A0 | P3: t2.B0 (+vmcnt4) | P4: t2.A1,B1
//        | P6: t3.A0 | P7: t3.B0 (+vmcnt4)
//   vmcnt(4)@P3 forces tile 2i+1 complete before P4..P7 reads it;
//   vmcnt(4)@P7 forces tile 2i+2 complete before next-iter P0..P3.
// ---------------------------------------------------------------------------
#define VM4  asm volatile("s_waitcnt vmcnt(4)" ::: "memory")
#define VM0  asm volatile("s_waitcnt vmcnt(0)" ::: "memory")
#define BAR  __builtin_amdgcn_s_barrier()
#define SCB  __builtin_amdgcn_sched_barrier(0)

// stage one 128-row half-slice of A (2 g2l16 per wave; all 8 waves cover 16KB)
#define STG_A(BUF, S, TL) do { \
    g2l16(Hb + (unsigned)((S)*163840 + (TL)*128) + agl,         ldsp + (BUF)*32768 + (S)*16384 + stl); \
    g2l16(Hb + (unsigned)((S)*163840 + (TL)*128 + 10240) + agl, ldsp + (BUF)*32768 + (S)*16384 + stl + 1024); \
  } while (0)
#define STG_B(BUF, S, TL) do { \
    g2l16(Wb + (unsigned)((S)*163840 + (TL)*128) + agl,         ldsp + 65536 + (BUF)*32768 + (S)*16384 + stl); \
    g2l16(Wb + (unsigned)((S)*163840 + (TL)*128 + 10240) + agl, ldsp + 65536 + (BUF)*32768 + (S)*16384 + stl + 1024); \
  } while (0)

#define PHASE(QM, QN, ABUF, BBUF, STAGE_STMT, WAIT_STMT) do { \
    bf16x8 af0[4], af1[4], bg0[2], bg1[2]; \
    _Pragma("unroll") for (int ii = 0; ii < 4; ++ii) { \
      af0[ii] = *(const bf16x8*)(ldsp + (ABUF)*32768 + (QM)*16384 + ii*2048 + aRowB + sx0); \
      af1[ii] = *(const bf16x8*)(ldsp + (ABUF)*32768 + (QM)*16384 + ii*2048 + aRowB + sx1); \
    } \
    _Pragma("unroll") for (int jj = 0; jj < 2; ++jj) { \
      bg0[jj] = *(const bf16x8*)(ldsp + 65536 + (BBUF)*32768 + (QN)*16384 + jj*2048 + bRowB + sx0); \
      bg1[jj] = *(const bf16x8*)(ldsp + 65536 + (BBUF)*32768 + (QN)*16384 + jj*2048 + bRowB + sx1); \
    } \
    STAGE_STMT; \
    WAIT_STMT; \
    BAR; SCB; \
    __builtin_amdgcn_s_setprio(1); \
    _Pragma("unroll") for (int ii = 0; ii < 4; ++ii) \
      _Pragma("unroll") for (int jj = 0; jj < 2; ++jj) { \
        acc[(QM)*4+ii][(QN)*2+jj] = __builtin_amdgcn_mfma_f32_16x16x32_bf16(af0[ii], bg0[jj], acc[(QM)*4+ii][(QN)*2+jj], 0, 0, 0); \
        acc[(QM)*4+ii][(QN)*2+jj] = __builtin_amdgcn_mfma_f32_16x16x32_bf16(af1[ii], bg1[jj], acc[(QM)*4+ii][(QN)*2+jj], 0, 0, 0); \
      } \
    __builtin_amdgcn_s_setprio(0); \
    BAR; SCB; \
  } while (0)

__global__ __launch_bounds__(512, 2) void gemm_kernel(
    const __bf16* __restrict__ H, const __bf16* __restrict__ W2t,
    const float* __restrict__ b2, float* __restrict__ C) {
    __shared__ __align__(128) char lds[131072];   // A: [0,64K), B: [64K,128K)

    // T1: XCD-aware swizzle. 800 blocks, 8 XCDs, 100 contiguous per XCD.
    const int bid = blockIdx.x;
    const int swz = (bid & 7) * 100 + (bid >> 3);
    const int mt = swz >> 2, nt = swz & 3;        // 200 M-tiles x 4 N-tiles
    const int m0 = mt * 256, n0 = nt * 256;

    const int tid = threadIdx.x;
    const int w = tid >> 6, l = tid & 63;
    const int wr = w >> 2, wc = w & 3;            // 2 x 4 wave grid
    const int lrow = l & 15, lk = l >> 4, l7 = l & 7, lhi = l >> 3;

    // staging per-lane constants: global col pre-swizzled so linear LDS dest
    // ends up with slot_lin = slot_global ^ (row&7)  (row&7 == l>>3 here).
    const unsigned swzb = (unsigned)(((l & 7) ^ lhi) * 16);
    const unsigned agl  = (unsigned)((w * 16 + lhi) * 1280) + swzb; // q=0
    const unsigned stl  = (unsigned)(w * 2048 + l * 16);            // q=0

    const char* Hb = (const char*)H   + (size_t)m0 * 1280;
    const char* Wb = (const char*)W2t + (size_t)n0 * 1280;
    char* ldsp = (char*)lds;

    // ds_read per-lane constants (read applies the same XOR swizzle)
    const unsigned aRowB = (unsigned)((wr * 64 + lrow) * 128);
    const unsigned bRowB = (unsigned)(wc * 4096 + lrow * 128);
    const unsigned sx0 = (unsigned)(((0 + lk) ^ l7) * 16);  // K-step 0 slot
    const unsigned sx1 = (unsigned)(((4 + lk) ^ l7) * 16);  // K-step 1 slot

    floatx4 acc[8][4] = {};

    // Prologue: tile0 (all 4 slices) + tile1 (A0,B0); force tile0, leave 4.
    STG_A(0, 0, 0); STG_A(0, 1, 0); STG_B(0, 0, 0); STG_B(0, 1, 0);
    STG_A(1, 0, 1); STG_B(1, 0, 1);
    VM4; BAR; SCB;

#pragma unroll 1
    for (int it = 0; it < 5; ++it) {            // 10 K-tiles, 2 per iter
        const int t1 = 2 * it + 1, t2 = 2 * it + 2, t3 = 2 * it + 3;
        const bool pf = (it < 4);               // t2,t3 <= 9
        PHASE(0, 0, 0, 0, { STG_A(1, 1, t1); STG_B(1, 1, t1); }, (void)0);
        PHASE(0, 1, 0, 0, (void)0, (void)0);
        PHASE(1, 0, 0, 0, { if (pf) STG_A(0, 0, t2); }, (void)0);
        PHASE(1, 1, 0, 0, { if (pf) STG_B(0, 0, t2); },
                          { if (it == 4) { VM0; } else { VM4; } });
        PHASE(0, 0, 1, 1, { if (pf) { STG_A(0, 1, t2); STG_B(0, 1, t2); } }, (void)0);
        PHASE(0, 1, 1, 1, (void)0, (void)0);
        PHASE(1, 0, 1, 1, { if (pf) STG_A(1, 0, t3); }, (void)0);
        PHASE(1, 1, 1, 1, { if (pf) STG_B(1, 0, t3); }, VM4);
    }

    // Epilogue: C/D layout col = lane&15 (N), row = (lane>>4)*4 + reg (M).
#pragma unroll
    for (int j = 0; j < 4; ++j) {
        const int col = n0 + (j >> 1) * 128 + wc * 32 + (j & 1) * 16 + lrow;
        const float bj = b2[col];
#pragma unroll
        for (int i = 0; i < 8; ++i) {
            const int row = m0 + (i >> 2) * 128 + wr * 64 + (i & 3) * 16 + lk * 4;
            float* Cp = C + (size_t)row * V_ + col;
#pragma unroll
            for (int rg = 0; rg < 4; ++rg)
                Cp[(size_t)rg * V_] = acc[i][j][rg] + bj;
        }
    }
}

// ---------------------------------------------------------------------------
extern "C" void kernel_launch(void* const* d_in, const int* in_sizes, int n_in,
                              void* d_out, int out_size, void* d_ws, size_t ws_size,
                              hipStream_t stream) {
    const float* enc = (const float*)d_in[0];
    const float* dec = (const float*)d_in[1];
    const float* W1  = (const float*)d_in[2];
    const float* b1  = (const float*)d_in[3];
    const float* W2  = (const float*)d_in[4];
    const float* b2  = (const float*)d_in[5];
    float* out = (float*)d_out;

    // Workspace layout (all 16B aligned), total ~69.3 MB:
    char* ws = (char*)d_ws;
    float*  encp = (float*)ws;                                   // 640*640*4
    float*  decp = (float*)(ws + 1638400);                       // 320*640*4
    __bf16* W2t  = (__bf16*)(ws + 1638400 + 819200);             // 1024*640*2
    __bf16* Hbuf = (__bf16*)(ws + 1638400 + 819200 + 1310720);   // 51200*640*2

    proj_kernel<<<dim3(20, 30), 256, 0, stream>>>(enc, dec, W1, encp, decp);
    w2t_kernel<<<dim3(32, 20), 256, 0, stream>>>(W2, W2t);
    hidden_kernel<<<16000, 256, 0, stream>>>(encp, decp, b1, Hbuf);
    gemm_kernel<<<800, 512, 0, stream>>>(Hbuf, W2t, b2, out);
}